// Round 2
// baseline (1025.551 us; speedup 1.0000x reference)
//
#include <hip/hip_runtime.h>

// Problem constants (from reference setup_inputs)
constexpr int N_NODES = 100000;
constexpr int N_EDGES = 1600000;
constexpr int E_TOT   = N_EDGES + N_NODES;   // with self-loops
constexpr int F_IN    = 128;
constexpr int F_H     = 64;
constexpr float NEG_SLOPE = 0.2f;

// Monotone float <-> uint key for atomicMax-based segment max.
// key(x) preserves float ordering as unsigned ordering; key init 0 acts as -inf
// (every node has a self-loop, so the final max is always a real edge score).
__device__ inline unsigned fkey(float x) {
    unsigned u = __float_as_uint(x);
    return (u & 0x80000000u) ? ~u : (u | 0x80000000u);
}
__device__ inline float fdec(unsigned k) {
    unsigned u = (k & 0x80000000u) ? (k & 0x7fffffffu) : ~k;
    return __uint_as_float(u);
}

// ---------------- Kernel A: h1 = x @ W1, alpha_s1/alpha_d1 fused ----------------
// Block = 256 threads, 16 nodes/block. W1 (128x64 = 32KB) staged in LDS once per
// block; 16 x-rows (8KB) staged too. Wave w handles nodes w, w+4, w+8, w+12;
// lane j owns output feature j (H == wave size == 64).
__global__ __launch_bounds__(256) void k_gemm1(
    const float* __restrict__ x, const float* __restrict__ W1,
    const float* __restrict__ a_s, const float* __restrict__ a_d,
    float* __restrict__ h1, float* __restrict__ as1, float* __restrict__ ad1)
{
    __shared__ float Ws[F_IN * F_H];   // 32 KB
    __shared__ float xs[16 * F_IN];    // 8 KB
    const int t = threadIdx.x;

    const float4* W4  = (const float4*)W1;
    float4*       Ws4 = (float4*)Ws;
    for (int i = t; i < (F_IN * F_H) / 4; i += 256) Ws4[i] = W4[i];

    const int n0 = blockIdx.x * 16;
    const int nrows = min(16, N_NODES - n0);
    const float4* x4  = (const float4*)(x + (size_t)n0 * F_IN);
    float4*       xs4 = (float4*)xs;
    for (int i = t; i < (nrows * F_IN) / 4; i += 256) xs4[i] = x4[i];
    __syncthreads();

    const int j  = t & 63;   // output feature
    const int wv = t >> 6;   // wave id 0..3
    float acc[4] = {0.f, 0.f, 0.f, 0.f};
    for (int k = 0; k < F_IN; ++k) {
        const float w = Ws[k * F_H + j];          // lanes j consecutive: 2-way bank alias (free)
#pragma unroll
        for (int q = 0; q < 4; ++q)
            acc[q] = fmaf(xs[(wv + q * 4) * F_IN + k], w, acc[q]);
    }

    const float asj = a_s[j], adj = a_d[j];
#pragma unroll
    for (int q = 0; q < 4; ++q) {
        const int n = n0 + wv + q * 4;
        if (n < N_NODES) {
            const float h = acc[q];
            h1[(size_t)n * F_H + j] = h;
            float vs = h * asj, vd = h * adj;
#pragma unroll
            for (int off = 32; off; off >>= 1) {
                vs += __shfl_down(vs, off, 64);
                vd += __shfl_down(vd, off, 64);
            }
            if (j == 0) { as1[n] = vs; ad1[n] = vd; }
        }
    }
}

// ---------------- Kernel B/E: edge scores + segment max ----------------
__global__ __launch_bounds__(256) void k_edge_max(
    const int* __restrict__ ei, const float* __restrict__ as, const float* __restrict__ ad,
    float* __restrict__ e, unsigned* __restrict__ mkey)
{
    const int i = blockIdx.x * 256 + threadIdx.x;
    if (i >= E_TOT) return;
    int s, d;
    if (i < N_EDGES) { s = ei[i]; d = ei[N_EDGES + i]; }
    else             { s = d = i - N_EDGES; }
    float v = as[s] + ad[d];
    v = v > 0.f ? v : NEG_SLOPE * v;
    e[i] = v;
    atomicMax(&mkey[d], fkey(v));
}

// ---------------- Kernel C: layer-1 aggregate (wave per edge) ----------------
// acc[dst][:] += p * h1[src][:]; denom[dst] += p. Denominator applied later.
__global__ __launch_bounds__(256) void k_agg1(
    const int* __restrict__ ei, const float* __restrict__ e,
    const unsigned* __restrict__ mkey, const float* __restrict__ h1,
    float* __restrict__ denom, float* __restrict__ acc)
{
    const int eid = blockIdx.x * 4 + (threadIdx.x >> 6);
    const int j   = threadIdx.x & 63;
    if (eid >= E_TOT) return;
    int s, d;
    if (eid < N_EDGES) { s = ei[eid]; d = ei[N_EDGES + eid]; }
    else               { s = d = eid - N_EDGES; }
    const float m = fdec(mkey[d]);
    const float p = __expf(e[eid] - m);
    if (j == 0) atomicAdd(&denom[d], p);
    atomicAdd(&acc[(size_t)d * F_H + j], p * h1[(size_t)s * F_H + j]);
}

// ---------------- Kernel D: layer-1 epilogue + layer-2 GEMM + alpha2 ----------------
__global__ __launch_bounds__(256) void k_epilogue1(
    const float* __restrict__ acc, const float* __restrict__ denom,
    const float* __restrict__ b1, const float* __restrict__ W2,
    const float* __restrict__ a_s2, const float* __restrict__ a_d2,
    float* __restrict__ h2, float* __restrict__ as2, float* __restrict__ ad2)
{
    const int n = blockIdx.x * 4 + (threadIdx.x >> 6);
    const int j = threadIdx.x & 63;
    if (n >= N_NODES) return;
    float v = acc[(size_t)n * F_H + j] / (denom[n] + 1e-16f) + b1[j];
    v = v > 0.f ? v : 0.f;                      // ReLU (dropout is identity in eval)
    float c0 = v * W2[j * 2 + 0];
    float c1 = v * W2[j * 2 + 1];
#pragma unroll
    for (int off = 32; off; off >>= 1) {
        c0 += __shfl_down(c0, off, 64);
        c1 += __shfl_down(c1, off, 64);
    }
    if (j == 0) {
        h2[n * 2 + 0] = c0;
        h2[n * 2 + 1] = c1;
        as2[n] = c0 * a_s2[0] + c1 * a_s2[1];
        ad2[n] = c0 * a_d2[0] + c1 * a_d2[1];
    }
}

// ---------------- Kernel F: layer-2 aggregate (thread per edge, C=2) ----------------
__global__ __launch_bounds__(256) void k_agg2(
    const int* __restrict__ ei, const float* __restrict__ e,
    const unsigned* __restrict__ mkey, const float* __restrict__ h2,
    float* __restrict__ denom, float* __restrict__ acc)
{
    const int i = blockIdx.x * 256 + threadIdx.x;
    if (i >= E_TOT) return;
    int s, d;
    if (i < N_EDGES) { s = ei[i]; d = ei[N_EDGES + i]; }
    else             { s = d = i - N_EDGES; }
    const float p = __expf(e[i] - fdec(mkey[d]));
    atomicAdd(&denom[d], p);
    atomicAdd(&acc[d * 2 + 0], p * h2[s * 2 + 0]);
    atomicAdd(&acc[d * 2 + 1], p * h2[s * 2 + 1]);
}

// ---------------- Kernel G: final normalize + bias ----------------
__global__ __launch_bounds__(256) void k_final(
    const float* __restrict__ acc, const float* __restrict__ denom,
    const float* __restrict__ b2, float* __restrict__ out)
{
    const int n = blockIdx.x * 256 + threadIdx.x;
    if (n >= N_NODES) return;
    const float inv = 1.f / (denom[n] + 1e-16f);
    out[n * 2 + 0] = acc[n * 2 + 0] * inv + b2[0];
    out[n * 2 + 1] = acc[n * 2 + 1] * inv + b2[1];
}

extern "C" void kernel_launch(void* const* d_in, const int* in_sizes, int n_in,
                              void* d_out, int out_size, void* d_ws, size_t ws_size,
                              hipStream_t stream)
{
    const float* x    = (const float*)d_in[0];
    const int*   ei   = (const int*)d_in[1];     // [2, E] int32
    const float* W1   = (const float*)d_in[2];
    const float* as1w = (const float*)d_in[3];
    const float* ad1w = (const float*)d_in[4];
    const float* b1   = (const float*)d_in[5];
    const float* W2   = (const float*)d_in[6];
    const float* as2w = (const float*)d_in[7];
    const float* ad2w = (const float*)d_in[8];
    const float* b2   = (const float*)d_in[9];
    float* out = (float*)d_out;

    // Workspace layout (floats). Zero-init region is contiguous: one memset.
    float* ws = (float*)d_ws;
    size_t off = 0;
    float*    h1     = ws + off; off += (size_t)N_NODES * F_H;   // 25.6 MB
    float*    zbase  = ws + off;
    float*    acc1   = ws + off; off += (size_t)N_NODES * F_H;   // 25.6 MB
    float*    acc2   = ws + off; off += (size_t)N_NODES * 2;
    unsigned* mkey1  = (unsigned*)(ws + off); off += N_NODES;
    float*    denom1 = ws + off; off += N_NODES;
    unsigned* mkey2  = (unsigned*)(ws + off); off += N_NODES;
    float*    denom2 = ws + off; off += N_NODES;
    const size_t zcount = (size_t)((ws + off) - zbase);
    float*    e1     = ws + off; off += E_TOT;                   // reused by layer 2
    float*    as1    = ws + off; off += N_NODES;
    float*    ad1    = ws + off; off += N_NODES;
    float*    h2     = ws + off; off += (size_t)N_NODES * 2;
    float*    as2    = ws + off; off += N_NODES;
    float*    ad2    = ws + off; off += N_NODES;
    // total ~63 MB

    hipMemsetAsync(zbase, 0, zcount * sizeof(float), stream);

    // Layer 1
    k_gemm1<<<(N_NODES + 15) / 16, 256, 0, stream>>>(x, W1, as1w, ad1w, h1, as1, ad1);
    k_edge_max<<<(E_TOT + 255) / 256, 256, 0, stream>>>(ei, as1, ad1, e1, mkey1);
    k_agg1<<<(E_TOT + 3) / 4, 256, 0, stream>>>(ei, e1, mkey1, h1, denom1, acc1);
    k_epilogue1<<<(N_NODES + 3) / 4, 256, 0, stream>>>(acc1, denom1, b1, W2, as2w, ad2w, h2, as2, ad2);

    // Layer 2 (e1 reused for scores)
    k_edge_max<<<(E_TOT + 255) / 256, 256, 0, stream>>>(ei, as2, ad2, e1, mkey2);
    k_agg2<<<(E_TOT + 255) / 256, 256, 0, stream>>>(ei, e1, mkey2, h2, denom2, acc2);
    k_final<<<(N_NODES + 255) / 256, 256, 0, stream>>>(acc2, denom2, b2, out);
}

// Round 3
// 481.320 us; speedup vs baseline: 2.1307x; 2.1307x over previous
//
#include <hip/hip_runtime.h>
#include <math.h>

constexpr int N_NODES = 100000;
constexpr int N_EDGES = 1600000;
constexpr int E_TOT   = N_EDGES + N_NODES;   // with self-loops
constexpr int F_IN    = 128;
constexpr int F_H     = 64;
constexpr float NEG_SLOPE = 0.2f;
constexpr int NB = (N_NODES + 255) / 256;    // 391 scan blocks

// ---------------- Kernel A: h1 = x @ W1, alpha_s1/alpha_d1 fused ----------------
__global__ __launch_bounds__(256) void k_gemm1(
    const float* __restrict__ x, const float* __restrict__ W1,
    const float* __restrict__ a_s, const float* __restrict__ a_d,
    float* __restrict__ h1, float* __restrict__ as1, float* __restrict__ ad1)
{
    __shared__ float Ws[F_IN * F_H];   // 32 KB
    __shared__ float xs[16 * F_IN];    // 8 KB
    const int t = threadIdx.x;

    const float4* W4  = (const float4*)W1;
    float4*       Ws4 = (float4*)Ws;
    for (int i = t; i < (F_IN * F_H) / 4; i += 256) Ws4[i] = W4[i];

    const int n0 = blockIdx.x * 16;
    const int nrows = min(16, N_NODES - n0);
    const float4* x4  = (const float4*)(x + (size_t)n0 * F_IN);
    float4*       xs4 = (float4*)xs;
    for (int i = t; i < (nrows * F_IN) / 4; i += 256) xs4[i] = x4[i];
    __syncthreads();

    const int j  = t & 63;
    const int wv = t >> 6;
    float acc[4] = {0.f, 0.f, 0.f, 0.f};
    for (int k = 0; k < F_IN; ++k) {
        const float w = Ws[k * F_H + j];
#pragma unroll
        for (int q = 0; q < 4; ++q)
            acc[q] = fmaf(xs[(wv + q * 4) * F_IN + k], w, acc[q]);
    }

    const float asj = a_s[j], adj = a_d[j];
#pragma unroll
    for (int q = 0; q < 4; ++q) {
        const int n = n0 + wv + q * 4;
        if (n < N_NODES) {
            const float h = acc[q];
            h1[(size_t)n * F_H + j] = h;
            float vs = h * asj, vd = h * adj;
#pragma unroll
            for (int off = 32; off; off >>= 1) {
                vs += __shfl_down(vs, off, 64);
                vd += __shfl_down(vd, off, 64);
            }
            if (j == 0) { as1[n] = vs; ad1[n] = vd; }
        }
    }
}

// ---------------- CSR build ----------------
__global__ __launch_bounds__(256) void k_hist(const int* __restrict__ ei, int* __restrict__ counts)
{
    const int i = blockIdx.x * 256 + threadIdx.x;
    if (i >= E_TOT) return;
    const int d = (i < N_EDGES) ? ei[N_EDGES + i] : (i - N_EDGES);
    atomicAdd(&counts[d], 1);
}

__global__ __launch_bounds__(256) void k_blocksum(const int* __restrict__ counts, int* __restrict__ blktot)
{
    __shared__ int s[256];
    const int t = threadIdx.x;
    const int i = blockIdx.x * 256 + t;
    s[t] = (i < N_NODES) ? counts[i] : 0;
    __syncthreads();
    for (int o = 128; o; o >>= 1) {
        if (t < o) s[t] += s[t + o];
        __syncthreads();
    }
    if (t == 0) blktot[blockIdx.x] = s[0];
}

__global__ __launch_bounds__(512) void k_scanblk(const int* __restrict__ blktot, int* __restrict__ blkoff)
{
    __shared__ int s[512];
    const int t = threadIdx.x;
    const int v = (t < NB) ? blktot[t] : 0;
    s[t] = v;
    __syncthreads();
    for (int o = 1; o < 512; o <<= 1) {
        int add = (t >= o) ? s[t - o] : 0;
        __syncthreads();
        s[t] += add;
        __syncthreads();
    }
    if (t < NB) blkoff[t] = s[t] - v;   // exclusive
}

__global__ __launch_bounds__(256) void k_scanfinal(
    const int* __restrict__ counts, const int* __restrict__ blkoff, int* __restrict__ row_start)
{
    __shared__ int s[256];
    const int t = threadIdx.x;
    const int i = blockIdx.x * 256 + t;
    const int v = (i < N_NODES) ? counts[i] : 0;
    s[t] = v;
    __syncthreads();
    for (int o = 1; o < 256; o <<= 1) {
        int add = (t >= o) ? s[t - o] : 0;
        __syncthreads();
        s[t] += add;
        __syncthreads();
    }
    if (i < N_NODES) row_start[i + 1] = blkoff[blockIdx.x] + s[t];  // inclusive -> start of i+1
    if (i == 0) row_start[0] = 0;
}

__global__ __launch_bounds__(256) void k_scatter(
    const int* __restrict__ ei, const int* __restrict__ row_start,
    int* __restrict__ cursor, int* __restrict__ csr)
{
    const int i = blockIdx.x * 256 + threadIdx.x;
    if (i >= E_TOT) return;
    int s, d;
    if (i < N_EDGES) { s = ei[i]; d = ei[N_EDGES + i]; }
    else             { s = d = i - N_EDGES; }
    const int pos = atomicAdd(&cursor[d], 1);
    csr[row_start[d] + pos] = s;
}

// ---------------- Layer-1 aggregate: wave per dst node, fused epilogue + layer-2 GEMM ----------------
// Online softmax over chunks of 64 edges; per-edge coalesced gather of h1[src][0..63].
__global__ __launch_bounds__(256) void k_agg1_csr(
    const int* __restrict__ row_start, const int* __restrict__ csr,
    const float* __restrict__ as1, const float* __restrict__ ad1,
    const float* __restrict__ h1, const float* __restrict__ b1,
    const float* __restrict__ W2, const float* __restrict__ a_s2, const float* __restrict__ a_d2,
    float* __restrict__ h2, float* __restrict__ as2, float* __restrict__ ad2)
{
    const int n = blockIdx.x * 4 + (threadIdx.x >> 6);
    const int j = threadIdx.x & 63;
    if (n >= N_NODES) return;

    const int r0 = row_start[n], r1 = row_start[n + 1];
    const float ad = ad1[n];

    float m = -INFINITY, den = 0.f, acc = 0.f;
    for (int base = r0; base < r1; base += 64) {
        const int cnt = min(64, r1 - base);
        int   sj = 0;
        float ej = -INFINITY;
        if (j < cnt) {
            sj = csr[base + j];
            float v = as1[sj] + ad;
            ej = v > 0.f ? v : NEG_SLOPE * v;
        }
        // wave max
        float cm = ej;
#pragma unroll
        for (int o = 32; o; o >>= 1) cm = fmaxf(cm, __shfl_xor(cm, o, 64));
        if (cm > m) {
            const float scale = __expf(m - cm);   // first chunk: exp(-inf) = 0
            den *= scale;
            acc *= scale;
            m = cm;
        }
        float pj = (j < cnt) ? __expf(ej - m) : 0.f;
        // wave sum of p
        float ps = pj;
#pragma unroll
        for (int o = 32; o; o >>= 1) ps += __shfl_xor(ps, o, 64);
        den += ps;
        // accumulate p_t * h1[s_t][j] over the chunk
        for (int t = 0; t < cnt; ++t) {
            const int   st = __shfl(sj, t, 64);
            const float pt = __shfl(pj, t, 64);
            acc = fmaf(pt, h1[(size_t)st * F_H + j], acc);
        }
    }

    // layer-1 epilogue: normalize + bias + ReLU
    float v = acc / (den + 1e-16f) + b1[j];
    v = v > 0.f ? v : 0.f;
    // layer-2 GEMM (64x2) + alpha2, reduced across the wave
    float c0 = v * W2[j * 2 + 0];
    float c1 = v * W2[j * 2 + 1];
#pragma unroll
    for (int o = 32; o; o >>= 1) {
        c0 += __shfl_xor(c0, o, 64);
        c1 += __shfl_xor(c1, o, 64);
    }
    if (j == 0) {
        h2[n * 2 + 0] = c0;
        h2[n * 2 + 1] = c1;
        as2[n] = c0 * a_s2[0] + c1 * a_s2[1];
        ad2[n] = c0 * a_d2[0] + c1 * a_d2[1];
    }
}

// ---------------- Layer-2 aggregate: thread per dst node (C=2), fused final ----------------
__global__ __launch_bounds__(256) void k_agg2_csr(
    const int* __restrict__ row_start, const int* __restrict__ csr,
    const float* __restrict__ as2, const float* __restrict__ ad2,
    const float* __restrict__ h2, const float* __restrict__ b2,
    float* __restrict__ out)
{
    const int n = blockIdx.x * 256 + threadIdx.x;
    if (n >= N_NODES) return;
    const int r0 = row_start[n], r1 = row_start[n + 1];
    const float ad = ad2[n];
    float m = -INFINITY, den = 0.f, a0 = 0.f, a1 = 0.f;
    const float2* h22 = (const float2*)h2;
    for (int idx = r0; idx < r1; ++idx) {
        const int s = csr[idx];
        float v = as2[s] + ad;
        v = v > 0.f ? v : NEG_SLOPE * v;
        if (v > m) {
            const float scale = __expf(m - v);
            den *= scale; a0 *= scale; a1 *= scale;
            m = v;
        }
        const float p = __expf(v - m);
        den += p;
        const float2 h = h22[s];
        a0 = fmaf(p, h.x, a0);
        a1 = fmaf(p, h.y, a1);
    }
    const float inv = 1.f / (den + 1e-16f);
    out[n * 2 + 0] = a0 * inv + b2[0];
    out[n * 2 + 1] = a1 * inv + b2[1];
}

extern "C" void kernel_launch(void* const* d_in, const int* in_sizes, int n_in,
                              void* d_out, int out_size, void* d_ws, size_t ws_size,
                              hipStream_t stream)
{
    const float* x    = (const float*)d_in[0];
    const int*   ei   = (const int*)d_in[1];     // [2, E] int32
    const float* W1   = (const float*)d_in[2];
    const float* as1w = (const float*)d_in[3];
    const float* ad1w = (const float*)d_in[4];
    const float* b1   = (const float*)d_in[5];
    const float* W2   = (const float*)d_in[6];
    const float* as2w = (const float*)d_in[7];
    const float* ad2w = (const float*)d_in[8];
    const float* b2   = (const float*)d_in[9];
    float* out = (float*)d_out;

    // Workspace layout
    float* ws = (float*)d_ws;
    size_t off = 0;
    float* h1  = ws + off; off += (size_t)N_NODES * F_H;   // 25.6 MB
    float* as1 = ws + off; off += N_NODES;
    float* ad1 = ws + off; off += N_NODES;
    float* h2  = ws + off; off += (size_t)N_NODES * 2;
    float* as2 = ws + off; off += N_NODES;
    float* ad2 = ws + off; off += N_NODES;
    int* zbase     = (int*)(ws + off);
    int* counts    = (int*)(ws + off); off += N_NODES;
    int* cursor    = (int*)(ws + off); off += N_NODES;
    const size_t zcount = 2 * (size_t)N_NODES;
    int* row_start = (int*)(ws + off); off += N_NODES + 1;
    int* blktot    = (int*)(ws + off); off += 512;
    int* blkoff    = (int*)(ws + off); off += 512;
    int* csr       = (int*)(ws + off); off += E_TOT;
    // total ~37 MB

    hipMemsetAsync(zbase, 0, zcount * sizeof(int), stream);

    // node-parallel GEMM (independent of CSR build)
    k_gemm1<<<(N_NODES + 15) / 16, 256, 0, stream>>>(x, W1, as1w, ad1w, h1, as1, ad1);

    // CSR by dst
    k_hist     <<<(E_TOT + 255) / 256, 256, 0, stream>>>(ei, counts);
    k_blocksum <<<NB, 256, 0, stream>>>(counts, blktot);
    k_scanblk  <<<1, 512, 0, stream>>>(blktot, blkoff);
    k_scanfinal<<<NB, 256, 0, stream>>>(counts, blkoff, row_start);
    k_scatter  <<<(E_TOT + 255) / 256, 256, 0, stream>>>(ei, row_start, cursor, csr);

    // Layer 1 aggregate + epilogue + layer-2 GEMM (fused)
    k_agg1_csr<<<(N_NODES + 3) / 4, 256, 0, stream>>>(
        row_start, csr, as1, ad1, h1, b1, W2, as2w, ad2w, h2, as2, ad2);

    // Layer 2 aggregate + final bias (fused)
    k_agg2_csr<<<NB, 256, 0, stream>>>(row_start, csr, as2, ad2, h2, b2, out);
}

// Round 4
// 408.999 us; speedup vs baseline: 2.5075x; 1.1768x over previous
//
#include <hip/hip_runtime.h>
#include <math.h>

constexpr int N_NODES = 100000;
constexpr int N_EDGES = 1600000;
constexpr int E_TOT   = N_EDGES + N_NODES;   // with self-loops
constexpr int F_IN    = 128;
constexpr int F_H     = 64;
constexpr float NEG_SLOPE = 0.2f;
constexpr int NB = (N_NODES + 255) / 256;    // 391 scan blocks

constexpr int GEMM_BLOCKS = N_NODES / 32;    // 3125 (100000 % 32 == 0)
constexpr int HIST_BLOCKS = (E_TOT + 255) / 256;

__device__ inline float lrelu(float v) { return v > 0.f ? v : NEG_SLOPE * v; }

// ---------------- Kernel A: h1 = x @ W1 (+ fused dst-histogram blocks) ----------------
// GEMM blocks [0, GEMM_BLOCKS): 32 rows/block, 8 rows/wave, lane j = output feature.
// W1 staged in LDS k-major with XOR swizzle so lane j's 4 consecutive-k weights are one
// conflict-free ds_read_b128. x rows staged row-major; read as broadcast b128.
// Blocks [GEMM_BLOCKS, GEMM_BLOCKS+HIST_BLOCKS): per-dst edge histogram (CSR step 1).
__global__ __launch_bounds__(256) void k_gemm1_hist(
    const float* __restrict__ x, const float* __restrict__ W1,
    const float* __restrict__ a_s, const float* __restrict__ a_d,
    float* __restrict__ h1, float* __restrict__ as1, float* __restrict__ ad1,
    const int* __restrict__ ei, int* __restrict__ counts)
{
    const int t = threadIdx.x;

    if (blockIdx.x >= GEMM_BLOCKS) {   // ---- histogram part ----
        const int i = (blockIdx.x - GEMM_BLOCKS) * 256 + t;
        if (i < E_TOT) {
            const int d = (i < N_EDGES) ? ei[N_EDGES + i] : (i - N_EDGES);
            atomicAdd(&counts[d], 1);
        }
        return;
    }

    __shared__ float Wsw[F_IN * F_H];   // 32 KB, swizzled k-major per feature row
    __shared__ float xs[32 * F_IN];     // 16 KB

    // stage W swizzled: logical (k, j) -> phys j*128 + ((k>>2) ^ (j&31))*4 + (k&3)
    for (int i = t; i < F_IN * F_H; i += 256) {
        const int k = i >> 6, j = i & 63;
        Wsw[j * F_IN + ((((k >> 2) ^ (j & 31)) << 2) | (k & 3))] = W1[i];
    }
    // stage 32 x rows (float4 coalesced)
    const int n0 = blockIdx.x * 32;
    {
        const float4* x4  = (const float4*)(x + (size_t)n0 * F_IN);
        float4*       xs4 = (float4*)xs;
        for (int i = t; i < 32 * F_IN / 4; i += 256) xs4[i] = x4[i];
    }
    __syncthreads();

    const int j   = t & 63;
    const int wv  = t >> 6;
    const int rb  = wv * 8;            // first row of this wave
    const int swz = j & 31;

    float acc[8] = {0.f, 0.f, 0.f, 0.f, 0.f, 0.f, 0.f, 0.f};
    const float* wrow = Wsw + j * F_IN;
    for (int k4 = 0; k4 < F_IN / 4; ++k4) {
        const float4 w = *(const float4*)(wrow + ((k4 ^ swz) << 2));
        const float* xk = xs + rb * F_IN + (k4 << 2);
#pragma unroll
        for (int q = 0; q < 8; ++q) {
            const float4 xq = *(const float4*)(xk + q * F_IN);
            acc[q] = fmaf(xq.x, w.x, acc[q]);
            acc[q] = fmaf(xq.y, w.y, acc[q]);
            acc[q] = fmaf(xq.z, w.z, acc[q]);
            acc[q] = fmaf(xq.w, w.w, acc[q]);
        }
    }

    const float asj = a_s[j], adj = a_d[j];
#pragma unroll
    for (int q = 0; q < 8; ++q) {
        const int n = n0 + rb + q;
        const float h = acc[q];
        h1[(size_t)n * F_H + j] = h;
        float vs = h * asj, vd = h * adj;
#pragma unroll
        for (int o = 32; o; o >>= 1) {
            vs += __shfl_down(vs, o, 64);
            vd += __shfl_down(vd, o, 64);
        }
        if (j == 0) { as1[n] = vs; ad1[n] = vd; }
    }
}

// ---------------- CSR build: scan + scatter ----------------
__global__ __launch_bounds__(256) void k_blocksum(const int* __restrict__ counts, int* __restrict__ blktot)
{
    __shared__ int s[256];
    const int t = threadIdx.x;
    const int i = blockIdx.x * 256 + t;
    s[t] = (i < N_NODES) ? counts[i] : 0;
    __syncthreads();
    for (int o = 128; o; o >>= 1) {
        if (t < o) s[t] += s[t + o];
        __syncthreads();
    }
    if (t == 0) blktot[blockIdx.x] = s[0];
}

__global__ __launch_bounds__(512) void k_scanblk(const int* __restrict__ blktot, int* __restrict__ blkoff)
{
    __shared__ int s[512];
    const int t = threadIdx.x;
    const int v = (t < NB) ? blktot[t] : 0;
    s[t] = v;
    __syncthreads();
    for (int o = 1; o < 512; o <<= 1) {
        int add = (t >= o) ? s[t - o] : 0;
        __syncthreads();
        s[t] += add;
        __syncthreads();
    }
    if (t < NB) blkoff[t] = s[t] - v;   // exclusive
}

__global__ __launch_bounds__(256) void k_scanfinal(
    const int* __restrict__ counts, const int* __restrict__ blkoff, int* __restrict__ row_start)
{
    __shared__ int s[256];
    const int t = threadIdx.x;
    const int i = blockIdx.x * 256 + t;
    const int v = (i < N_NODES) ? counts[i] : 0;
    s[t] = v;
    __syncthreads();
    for (int o = 1; o < 256; o <<= 1) {
        int add = (t >= o) ? s[t - o] : 0;
        __syncthreads();
        s[t] += add;
        __syncthreads();
    }
    if (i < N_NODES) row_start[i + 1] = blkoff[blockIdx.x] + s[t];
    if (i == 0) row_start[0] = 0;
}

__global__ __launch_bounds__(256) void k_scatter(
    const int* __restrict__ ei, const int* __restrict__ row_start,
    int* __restrict__ cursor, int* __restrict__ csr)
{
    const int i = blockIdx.x * 256 + threadIdx.x;
    if (i >= E_TOT) return;
    int s, d;
    if (i < N_EDGES) { s = ei[i]; d = ei[N_EDGES + i]; }
    else             { s = d = i - N_EDGES; }
    const int pos = atomicAdd(&cursor[d], 1);
    csr[row_start[d] + pos] = s;
}

// ---------------- Layer-1 aggregate: wave per dst, two-phase softmax, unrolled gather ----------------
// max_e = lrelu(max_s(as1[s]) + ad) because lrelu is monotone increasing — no online rescale.
__global__ __launch_bounds__(256) void k_agg1_csr(
    const int* __restrict__ row_start, const int* __restrict__ csr,
    const float* __restrict__ as1, const float* __restrict__ ad1,
    const float* __restrict__ h1, const float* __restrict__ b1,
    const float* __restrict__ W2, const float* __restrict__ a_s2, const float* __restrict__ a_d2,
    float* __restrict__ h2, float* __restrict__ as2, float* __restrict__ ad2)
{
    const int n = blockIdx.x * 4 + (threadIdx.x >> 6);
    const int j = threadIdx.x & 63;
    if (n >= N_NODES) return;

    const int r0 = row_start[n], r1 = row_start[n + 1];
    const int deg = r1 - r0;
    const float ad = ad1[n];
    const float* __restrict__ hj = h1 + j;

    float acc = 0.f, den_l = 0.f;

    if (deg <= 64) {                     // fast path: one chunk, scores live in registers
        int   sj = 0;
        float aj = -INFINITY;
        if (j < deg) { sj = csr[r0 + j]; aj = as1[sj]; }
        float rm = aj;
#pragma unroll
        for (int o = 32; o; o >>= 1) rm = fmaxf(rm, __shfl_xor(rm, o, 64));
        const float mv = lrelu(rm + ad);
        float pj = 0.f;
        if (j < deg) pj = __expf(lrelu(aj + ad) - mv);
        den_l = pj;

        int t = 0;
        for (; t + 4 <= deg; t += 4) {
            const int   s0 = __shfl(sj, t,     64), s1 = __shfl(sj, t + 1, 64),
                        s2 = __shfl(sj, t + 2, 64), s3 = __shfl(sj, t + 3, 64);
            const float p0 = __shfl(pj, t,     64), p1 = __shfl(pj, t + 1, 64),
                        p2 = __shfl(pj, t + 2, 64), p3 = __shfl(pj, t + 3, 64);
            const float v0 = hj[(size_t)s0 << 6], v1 = hj[(size_t)s1 << 6],
                        v2 = hj[(size_t)s2 << 6], v3 = hj[(size_t)s3 << 6];
            acc = fmaf(p0, v0, acc); acc = fmaf(p1, v1, acc);
            acc = fmaf(p2, v2, acc); acc = fmaf(p3, v3, acc);
        }
        for (; t < deg; ++t) {
            const int   s0 = __shfl(sj, t, 64);
            const float p0 = __shfl(pj, t, 64);
            acc = fmaf(p0, hj[(size_t)s0 << 6], acc);
        }
    } else {                              // generic path: two passes over chunks
        float rml = -INFINITY;
        for (int idx = r0 + j; idx < r1; idx += 64) rml = fmaxf(rml, as1[csr[idx]]);
        float rm = rml;
#pragma unroll
        for (int o = 32; o; o >>= 1) rm = fmaxf(rm, __shfl_xor(rm, o, 64));
        const float mv = lrelu(rm + ad);

        for (int base = r0; base < r1; base += 64) {
            const int cnt = min(64, r1 - base);
            int sj = 0; float pj = 0.f;
            if (j < cnt) { sj = csr[base + j]; pj = __expf(lrelu(as1[sj] + ad) - mv); }
            den_l += pj;
            int t = 0;
            for (; t + 4 <= cnt; t += 4) {
                const int   s0 = __shfl(sj, t,     64), s1 = __shfl(sj, t + 1, 64),
                            s2 = __shfl(sj, t + 2, 64), s3 = __shfl(sj, t + 3, 64);
                const float p0 = __shfl(pj, t,     64), p1 = __shfl(pj, t + 1, 64),
                            p2 = __shfl(pj, t + 2, 64), p3 = __shfl(pj, t + 3, 64);
                const float v0 = hj[(size_t)s0 << 6], v1 = hj[(size_t)s1 << 6],
                            v2 = hj[(size_t)s2 << 6], v3 = hj[(size_t)s3 << 6];
                acc = fmaf(p0, v0, acc); acc = fmaf(p1, v1, acc);
                acc = fmaf(p2, v2, acc); acc = fmaf(p3, v3, acc);
            }
            for (; t < cnt; ++t) {
                const int   s0 = __shfl(sj, t, 64);
                const float p0 = __shfl(pj, t, 64);
                acc = fmaf(p0, hj[(size_t)s0 << 6], acc);
            }
        }
    }

    float den = den_l;
#pragma unroll
    for (int o = 32; o; o >>= 1) den += __shfl_xor(den, o, 64);

    // layer-1 epilogue + 64x2 layer-2 GEMM + alpha2
    float v = acc / (den + 1e-16f) + b1[j];
    v = v > 0.f ? v : 0.f;
    float c0 = v * W2[j * 2 + 0];
    float c1 = v * W2[j * 2 + 1];
#pragma unroll
    for (int o = 32; o; o >>= 1) {
        c0 += __shfl_xor(c0, o, 64);
        c1 += __shfl_xor(c1, o, 64);
    }
    if (j == 0) {
        h2[n * 2 + 0] = c0;
        h2[n * 2 + 1] = c1;
        as2[n] = c0 * a_s2[0] + c1 * a_s2[1];
        ad2[n] = c0 * a_d2[0] + c1 * a_d2[1];
    }
}

// ---------------- Layer-2 aggregate: thread per dst, two-pass, unrolled ----------------
__global__ __launch_bounds__(256) void k_agg2_csr(
    const int* __restrict__ row_start, const int* __restrict__ csr,
    const float* __restrict__ as2, const float* __restrict__ ad2,
    const float* __restrict__ h2, const float* __restrict__ b2,
    float* __restrict__ out)
{
    const int n = blockIdx.x * 256 + threadIdx.x;
    if (n >= N_NODES) return;
    const int r0 = row_start[n], r1 = row_start[n + 1];
    const float ad = ad2[n];
    const float2* h22 = (const float2*)h2;

    // pass 1: raw max (lrelu monotone)
    float rm = -INFINITY;
    int idx = r0;
    for (; idx + 4 <= r1; idx += 4) {
        const int s0 = csr[idx], s1 = csr[idx + 1], s2 = csr[idx + 2], s3 = csr[idx + 3];
        const float a0 = as2[s0], a1 = as2[s1], a2 = as2[s2], a3 = as2[s3];
        rm = fmaxf(rm, fmaxf(fmaxf(a0, a1), fmaxf(a2, a3)));
    }
    for (; idx < r1; ++idx) rm = fmaxf(rm, as2[csr[idx]]);
    const float mv = lrelu(rm + ad);

    // pass 2: exp + weighted accumulate
    float den = 0.f, x0 = 0.f, x1 = 0.f;
    idx = r0;
    for (; idx + 2 <= r1; idx += 2) {
        const int s0 = csr[idx], s1 = csr[idx + 1];
        const float  a0 = as2[s0], a1 = as2[s1];
        const float2 g0 = h22[s0], g1 = h22[s1];
        const float p0 = __expf(lrelu(a0 + ad) - mv);
        const float p1 = __expf(lrelu(a1 + ad) - mv);
        den += p0 + p1;
        x0 = fmaf(p0, g0.x, fmaf(p1, g1.x, x0));
        x1 = fmaf(p0, g0.y, fmaf(p1, g1.y, x1));
    }
    for (; idx < r1; ++idx) {
        const int s0 = csr[idx];
        const float p0 = __expf(lrelu(as2[s0] + ad) - mv);
        const float2 g0 = h22[s0];
        den += p0;
        x0 = fmaf(p0, g0.x, x0);
        x1 = fmaf(p0, g0.y, x1);
    }
    const float inv = 1.f / (den + 1e-16f);
    out[n * 2 + 0] = x0 * inv + b2[0];
    out[n * 2 + 1] = x1 * inv + b2[1];
}

extern "C" void kernel_launch(void* const* d_in, const int* in_sizes, int n_in,
                              void* d_out, int out_size, void* d_ws, size_t ws_size,
                              hipStream_t stream)
{
    const float* x    = (const float*)d_in[0];
    const int*   ei   = (const int*)d_in[1];     // [2, E] int32
    const float* W1   = (const float*)d_in[2];
    const float* as1w = (const float*)d_in[3];
    const float* ad1w = (const float*)d_in[4];
    const float* b1   = (const float*)d_in[5];
    const float* W2   = (const float*)d_in[6];
    const float* as2w = (const float*)d_in[7];
    const float* ad2w = (const float*)d_in[8];
    const float* b2   = (const float*)d_in[9];
    float* out = (float*)d_out;

    // Workspace layout
    float* ws = (float*)d_ws;
    size_t off = 0;
    float* h1  = ws + off; off += (size_t)N_NODES * F_H;   // 25.6 MB
    float* as1 = ws + off; off += N_NODES;
    float* ad1 = ws + off; off += N_NODES;
    float* h2  = ws + off; off += (size_t)N_NODES * 2;
    float* as2 = ws + off; off += N_NODES;
    float* ad2 = ws + off; off += N_NODES;
    int* zbase     = (int*)(ws + off);
    int* counts    = (int*)(ws + off); off += N_NODES;
    int* cursor    = (int*)(ws + off); off += N_NODES;
    const size_t zcount = 2 * (size_t)N_NODES;
    int* row_start = (int*)(ws + off); off += N_NODES + 1;
    int* blktot    = (int*)(ws + off); off += 512;
    int* blkoff    = (int*)(ws + off); off += 512;
    int* csr       = (int*)(ws + off); off += E_TOT;

    hipMemsetAsync(zbase, 0, zcount * sizeof(int), stream);

    // GEMM (3125 blocks) + dst histogram (6641 blocks) in one dispatch
    k_gemm1_hist<<<GEMM_BLOCKS + HIST_BLOCKS, 256, 0, stream>>>(
        x, W1, as1w, ad1w, h1, as1, ad1, ei, counts);

    k_blocksum <<<NB, 256, 0, stream>>>(counts, blktot);
    k_scanblk  <<<1, 512, 0, stream>>>(blktot, blkoff);
    k_scanfinal<<<NB, 256, 0, stream>>>(counts, blkoff, row_start);
    k_scatter  <<<HIST_BLOCKS, 256, 0, stream>>>(ei, row_start, cursor, csr);

    k_agg1_csr<<<(N_NODES + 3) / 4, 256, 0, stream>>>(
        row_start, csr, as1, ad1, h1, b1, W2, as2w, ad2w, h2, as2, ad2);

    k_agg2_csr<<<NB, 256, 0, stream>>>(row_start, csr, as2, ad2, h2, b2, out);
}